// Round 7
// baseline (358.281 us; speedup 1.0000x reference)
//
#include <hip/hip_runtime.h>
#include <hip/hip_fp16.h>

// GraphSAGE 3-layer + head, MI355X.
// R6: gathers restructured for 16B/lane loads: agg128 = 4 edge-groups x 16 lanes
//   (one dwordx4 inst gathers 4 rows = 1KB), agg64 = 8 groups x 8 lanes.
//   4x fewer load insts, 8 rows in flight/wave, masked group-parallel tail.
//   fp8 payload rejected (error model: ~5-8e-5 > 2.6e-5 threshold).
// CSR: multi-block radix partition (R5). GEMMs: bf16 MFMA 16x16x32, W hi+lo in
// L1, hi-only in L2/L3. Head folded into Wcomb + fused into final agg.

typedef __attribute__((ext_vector_type(8))) short bf16x8;
typedef __attribute__((ext_vector_type(4))) float f32x4;

struct Seg { const unsigned short* A; const unsigned short* W; int lda; int ldw; int K; };
struct Segs { Seg s[4]; int n; };

__device__ __forceinline__ unsigned short f2bf(float x) {
  unsigned u = __float_as_uint(x);
  u += 0x7FFF + ((u >> 16) & 1);   // RNE
  return (unsigned short)(u >> 16);
}
__device__ __forceinline__ unsigned short f2h(float x) {
  return __half_as_ushort(__float2half(x));
}
__device__ __forceinline__ float2 h2f(unsigned u) {
  __half2 h = *reinterpret_cast<__half2*>(&u);
  return __half22float2(h);
}
__device__ __forceinline__ void acc8(float* acc, uint4 v) {
  float2 a = h2f(v.x), b = h2f(v.y), c = h2f(v.z), d = h2f(v.w);
  acc[0] += a.x; acc[1] += a.y; acc[2] += b.x; acc[3] += b.y;
  acc[4] += c.x; acc[5] += c.y; acc[6] += d.x; acc[7] += d.y;
}

// ---------------- CSR build: multi-block radix partition ----------------
__global__ __launch_bounds__(256) void hist_k(const int* __restrict__ tgt, int* __restrict__ histT,
                                              int E, int NB, int CH) {
  extern __shared__ int sh[];
  int g = blockIdx.x, tid = threadIdx.x;
  for (int b = tid; b < NB; b += 256) sh[b] = 0;
  __syncthreads();
  int eb = g * CH, ee = min(eb + CH, E);
  for (int i = eb + tid; i < ee; i += 256)
    atomicAdd(&sh[tgt[i] >> 6], 1);
  __syncthreads();
  for (int b = tid; b < NB; b += 256) histT[b * 64 + g] = sh[b];
}

__global__ __launch_bounds__(256) void scanb_k(int* __restrict__ histT, int* __restrict__ bcnt, int NB) {
  int wv = threadIdx.x >> 6, lane = threadIdx.x & 63;
  int b = blockIdx.x * 4 + wv;
  if (b >= NB) return;
  int v = histT[b * 64 + lane];
  int x = v;
#pragma unroll
  for (int o = 1; o < 64; o <<= 1) {
    int y = __shfl_up(x, o);
    if (lane >= o) x += y;
  }
  histT[b * 64 + lane] = x - v;
  if (lane == 63) bcnt[b] = x;
}

__global__ __launch_bounds__(1024) void bscan_k(const int* __restrict__ bcnt, int* __restrict__ boff,
                                                int* __restrict__ row_ptr, int NB, int E, int N) {
  __shared__ int sh[1024];
  int tid = threadIdx.x;
  int v = (tid < NB) ? bcnt[tid] : 0;
  int val = v;
  sh[tid] = val;
  __syncthreads();
  for (int o = 1; o < 1024; o <<= 1) {
    int t = (tid >= o) ? sh[tid - o] : 0;
    __syncthreads();
    val += t;
    sh[tid] = val;
    __syncthreads();
  }
  if (tid < NB) boff[tid] = val - v;
  if (tid == NB - 1) boff[NB] = val;
  if (tid == 0) row_ptr[N] = E;
}

__global__ __launch_bounds__(256) void scatter_k(const int* __restrict__ src, const int* __restrict__ tgt,
                                                 const int* __restrict__ boff, const int* __restrict__ histT,
                                                 unsigned* __restrict__ vals, int E, int NB, int CH) {
  extern __shared__ int sh[];
  int g = blockIdx.x, tid = threadIdx.x;
  for (int b = tid; b < NB; b += 256) sh[b] = boff[b] + histT[b * 64 + g];
  __syncthreads();
  int eb = g * CH, ee = min(eb + CH, E);
  for (int i = eb + tid; i < ee; i += 256) {
    int t = tgt[i], s = src[i];
    int pos = atomicAdd(&sh[t >> 6], 1);
    vals[pos] = (unsigned)s | ((unsigned)(t & 63) << 17);
  }
}

__global__ __launch_bounds__(256) void bsort_k(const unsigned* __restrict__ vals, const int* __restrict__ boff,
                                               int* __restrict__ row_ptr, int* __restrict__ srcs, int N) {
  int b = blockIdx.x;
  int base = b << 6;
  int s0 = boff[b], s1 = boff[b + 1];
  __shared__ int hist[64], excl[64], cur[64];
  int tid = threadIdx.x;
  if (tid < 64) { hist[tid] = 0; cur[tid] = 0; }
  __syncthreads();
  for (int i = s0 + tid; i < s1; i += 256)
    atomicAdd(&hist[(vals[i] >> 17) & 63], 1);
  __syncthreads();
  if (tid < 64) {
    int v = hist[tid];
    int x = v;
#pragma unroll
    for (int o = 1; o < 64; o <<= 1) {
      int y = __shfl_up(x, o);
      if (tid >= o) x += y;
    }
    excl[tid] = x - v;
    int node = base + tid;
    if (node < N) row_ptr[node] = s0 + x - v;
  }
  __syncthreads();
  for (int i = s0 + tid; i < s1; i += 256) {
    unsigned v = vals[i];
    int l = (v >> 17) & 63;
    int pos = s0 + excl[l] + atomicAdd(&cur[l], 1);
    srcs[pos] = (int)(v & 0x1FFFF);
  }
}

// ---------------- merged prep: conv + weight packs + head fold ----------------
__device__ __forceinline__ void split_store(float v, unsigned short* hi, unsigned short* lo, int idx) {
  unsigned short h = f2bf(v);
  float hf = __uint_as_float(((unsigned)h) << 16);
  hi[idx] = h;
  lo[idx] = f2bf(v - hf);
}

__global__ __launch_bounds__(256) void prep_k(
    const float* __restrict__ x, unsigned short* __restrict__ xb, unsigned short* __restrict__ xh, int nbConv, int n4,
    const float* __restrict__ Wf_l, const float* __restrict__ Wf_r,
    unsigned short* __restrict__ Wt1hi, unsigned short* __restrict__ Wt1lo,
    const float* __restrict__ W0_l, const float* __restrict__ W0_r, unsigned short* __restrict__ Wt2hi,
    const float* __restrict__ W1_l, const float* __restrict__ W1_r, unsigned short* __restrict__ Wt3hi,
    const float* __restrict__ Wlin, const float* __restrict__ blin,
    const float* __restrict__ Wlin2, const float* __restrict__ blin2,
    float* __restrict__ Wc, float* __restrict__ bc) {
  int b = blockIdx.x, t = threadIdx.x;
  if (b < nbConv) {
    int i = b * 256 + t;
    if (i < n4) {
      float4 v = ((const float4*)x)[i];
      ((ushort2*)xb)[i * 2]     = make_ushort2(f2bf(v.x), f2bf(v.y));
      ((ushort2*)xb)[i * 2 + 1] = make_ushort2(f2bf(v.z), f2bf(v.w));
      ((ushort2*)xh)[i * 2]     = make_ushort2(f2h(v.x), f2h(v.y));
      ((ushort2*)xh)[i * 2 + 1] = make_ushort2(f2h(v.z), f2h(v.w));
    }
    return;
  }
  b -= nbConv;
  if (b < 128) {             // L1 k-split pack, hi+lo: Wt1[n][k] (256 x 128)
    int idx = b * 256 + t;
    int n = idx >> 7, k = idx & 127;
    float v = (k < 64) ? Wf_l[k * 256 + n] : Wf_r[(k - 64) * 256 + n];
    split_store(v, Wt1hi, Wt1lo, idx);
    return;
  }
  b -= 128;
  if (b < 256) {             // L2 n-split pack, hi only: Wt2[n][k] (256 x 256)
    int idx = b * 256 + t;
    int n = idx >> 8, k = idx & 255;
    float v = (n < 128) ? W0_l[k * 128 + n] : W0_r[k * 128 + (n - 128)];
    Wt2hi[idx] = f2bf(v);
    return;
  }
  b -= 256;
  if (b < 128) {             // L3 n-split pack, hi only: Wt3[n][k] (256 x 128)
    int idx = b * 256 + t;
    int n = idx >> 7, k = idx & 127;
    float v = (n < 128) ? W1_l[k * 128 + n] : W1_r[k * 128 + (n - 128)];
    Wt3hi[idx] = f2bf(v);
    return;
  }
  b -= 128;
  {                          // head fold: 4 blocks
    int idx = b * 256 + t;
    if (idx < 1024) {
      int i = idx >> 3, j = idx & 7;
      float acc = 0.f;
      for (int k = 0; k < 128; ++k) acc = fmaf(Wlin[i * 128 + k], Wlin2[k * 8 + j], acc);
      Wc[idx] = acc;
    }
    if (idx < 8) {
      float acc = blin2[idx];
      for (int k = 0; k < 128; ++k) acc = fmaf(blin[k], Wlin2[k * 8 + idx], acc);
      bc[idx] = acc;
    }
  }
}

// ---------------- aggregation ----------------
// wave per node, D=64: 8 edge-groups x 8 lanes, 16B (8 fp16 dims) per lane.
__global__ __launch_bounds__(256) void agg_mean64_k(const unsigned short* __restrict__ xh, const int* __restrict__ rp,
                                                    const int* __restrict__ srcs, unsigned short* __restrict__ mb, int n) {
  int w = threadIdx.x >> 6, lane = threadIdx.x & 63;
  int node = blockIdx.x * 4 + w;
  if (node >= n) return;
  int grp = lane >> 3, sl = lane & 7;
  int d0 = sl * 8;
  int s0 = rp[node], s1 = rp[node + 1];
  float acc[8] = {0.f, 0.f, 0.f, 0.f, 0.f, 0.f, 0.f, 0.f};
  int e = s0;
  for (; e + 16 <= s1; e += 16) {
    int ia = srcs[e + grp];
    int ib = srcs[e + 8 + grp];
    uint4 va = *(const uint4*)&xh[(size_t)ia * 64 + d0];
    uint4 vb = *(const uint4*)&xh[(size_t)ib * 64 + d0];
    acc8(acc, va);
    acc8(acc, vb);
  }
  for (; e < s1; e += 8) {
    int idx = e + grp;
    if (idx < s1) {
      int ia = srcs[idx];
      uint4 va = *(const uint4*)&xh[(size_t)ia * 64 + d0];
      acc8(acc, va);
    }
  }
#pragma unroll
  for (int j = 0; j < 8; ++j) {
    acc[j] += __shfl_xor(acc[j], 8);
    acc[j] += __shfl_xor(acc[j], 16);
    acc[j] += __shfl_xor(acc[j], 32);
  }
  int deg = s1 - s0;
  float inv = 1.f / (float)(deg > 0 ? deg : 1);
  if (grp == 0) {
    unsigned p0 = (unsigned)f2bf(acc[0] * inv) | ((unsigned)f2bf(acc[1] * inv) << 16);
    unsigned p1 = (unsigned)f2bf(acc[2] * inv) | ((unsigned)f2bf(acc[3] * inv) << 16);
    unsigned p2 = (unsigned)f2bf(acc[4] * inv) | ((unsigned)f2bf(acc[5] * inv) << 16);
    unsigned p3 = (unsigned)f2bf(acc[6] * inv) | ((unsigned)f2bf(acc[7] * inv) << 16);
    *(uint4*)&mb[(size_t)node * 64 + d0] = make_uint4(p0, p1, p2, p3);
  }
}

// wave per node, D=128: 4 edge-groups x 16 lanes, 16B (8 fp16 dims) per lane.
// OUTMODE 1: hout = bf16 h (N x 128). OUTMODE 2: fused head -> out fp32 (N x 8).
template <int OUTMODE>
__global__ __launch_bounds__(256) void agg128_k(const unsigned short* __restrict__ yb,
                                                const unsigned short* __restrict__ zb,
                                                const float* __restrict__ bias,
                                                const int* __restrict__ rp, const int* __restrict__ srcs,
                                                void* __restrict__ hout,
                                                const float* __restrict__ Wc, const float* __restrict__ bc, int n) {
  int w = threadIdx.x >> 6, lane = threadIdx.x & 63;
  int node = blockIdx.x * 4 + w;
  if (node >= n) return;
  int grp = lane >> 4, sl = lane & 15;
  int d0 = sl * 8;
  int s0 = rp[node], s1 = rp[node + 1];
  float acc[8] = {0.f, 0.f, 0.f, 0.f, 0.f, 0.f, 0.f, 0.f};
  int e = s0;
  for (; e + 8 <= s1; e += 8) {
    int ia = srcs[e + grp];
    int ib = srcs[e + 4 + grp];
    uint4 va = *(const uint4*)&yb[(size_t)ia * 128 + d0];
    uint4 vb = *(const uint4*)&yb[(size_t)ib * 128 + d0];
    acc8(acc, va);
    acc8(acc, vb);
  }
  for (; e < s1; e += 4) {
    int idx = e + grp;
    if (idx < s1) {
      int ia = srcs[idx];
      uint4 va = *(const uint4*)&yb[(size_t)ia * 128 + d0];
      acc8(acc, va);
    }
  }
#pragma unroll
  for (int j = 0; j < 8; ++j) {
    acc[j] += __shfl_xor(acc[j], 16);
    acc[j] += __shfl_xor(acc[j], 32);
  }
  int deg = s1 - s0;
  float inv = 1.f / (float)(deg > 0 ? deg : 1);
  uint4 zv = *(const uint4*)&zb[(size_t)node * 128 + d0];
  float2 za = h2f(zv.x), zc = h2f(zv.y), zd = h2f(zv.z), ze = h2f(zv.w);
  float zf[8] = {za.x, za.y, zc.x, zc.y, zd.x, zd.y, ze.x, ze.y};
  float4 b0v = *(const float4*)&bias[d0];
  float4 b1v = *(const float4*)&bias[d0 + 4];
  float bf8[8] = {b0v.x, b0v.y, b0v.z, b0v.w, b1v.x, b1v.y, b1v.z, b1v.w};
  float o[8];
#pragma unroll
  for (int j = 0; j < 8; ++j)
    o[j] = fmaxf(fmaf(acc[j], inv, zf[j] + bf8[j]), 0.f);

  if (OUTMODE == 1) {
    if (grp == 0) {
      unsigned p0 = (unsigned)f2bf(o[0]) | ((unsigned)f2bf(o[1]) << 16);
      unsigned p1 = (unsigned)f2bf(o[2]) | ((unsigned)f2bf(o[3]) << 16);
      unsigned p2 = (unsigned)f2bf(o[4]) | ((unsigned)f2bf(o[5]) << 16);
      unsigned p3 = (unsigned)f2bf(o[6]) | ((unsigned)f2bf(o[7]) << 16);
      *(uint4*)&((unsigned short*)hout)[(size_t)node * 128 + d0] = make_uint4(p0, p1, p2, p3);
    }
  } else {
    // fused head: lane owns dims d0..d0+7; partials then 16-lane butterfly
    float a8[8] = {0.f, 0.f, 0.f, 0.f, 0.f, 0.f, 0.f, 0.f};
#pragma unroll
    for (int j = 0; j < 8; ++j) {
      const float4* wr = (const float4*)&Wc[(d0 + j) * 8];
      float4 w0 = wr[0], w1 = wr[1];
      a8[0] = fmaf(o[j], w0.x, a8[0]); a8[1] = fmaf(o[j], w0.y, a8[1]);
      a8[2] = fmaf(o[j], w0.z, a8[2]); a8[3] = fmaf(o[j], w0.w, a8[3]);
      a8[4] = fmaf(o[j], w1.x, a8[4]); a8[5] = fmaf(o[j], w1.y, a8[5]);
      a8[6] = fmaf(o[j], w1.z, a8[6]); a8[7] = fmaf(o[j], w1.w, a8[7]);
    }
#pragma unroll
    for (int off = 1; off <= 8; off <<= 1) {
#pragma unroll
      for (int j = 0; j < 8; ++j) a8[j] += __shfl_xor(a8[j], off);
    }
    if (lane == 0) {
      float* op = (float*)hout + (size_t)node * 8;
      *(float4*)op       = make_float4(a8[0] + bc[0], a8[1] + bc[1], a8[2] + bc[2], a8[3] + bc[3]);
      *(float4*)(op + 4) = make_float4(a8[4] + bc[4], a8[5] + bc[5], a8[6] + bc[6], a8[7] + bc[7]);
    }
  }
}

// ---------------- MFMA GEMM ----------------
// Block tile 128x128, 4 waves (2x2), each wave 64x64 via 4x4 frags of 16x16x32 bf16 MFMA.
// MODE 0: fp16 out, split into Y (cols 0..127) / Z (cols 128..255), ld 128.
// MODE 1: bias+relu -> bf16 out Ob (ldc 256).
template <int MODE>
__global__ __launch_bounds__(256) void gemm_mfma_k(Segs segs, const float* __restrict__ bias,
                                                   unsigned short* __restrict__ Y, unsigned short* __restrict__ Z,
                                                   unsigned short* __restrict__ Ob, int ldc) {
  __shared__ unsigned short Asl[128 * 32];
  __shared__ unsigned short Wsl[128 * 32];
  int tid = threadIdx.x;
  int lane = tid & 63, wave = tid >> 6;
  int wm = wave & 1, wn = wave >> 1;
  int rowBase = blockIdx.x * 128, colBase = blockIdx.y * 128;
  f32x4 acc[4][4] = {};

  int c0 = tid, c1 = tid + 256;
  int r0 = c0 >> 2, q0 = c0 & 3;
  int r1 = c1 >> 2, q1 = c1 & 3;
  int ml = lane & 15, qq = lane >> 4;

  for (int si = 0; si < segs.n; ++si) {
    const unsigned short* Aseg = segs.s[si].A;
    const unsigned short* Wseg = segs.s[si].W;
    int lda = segs.s[si].lda, ldw = segs.s[si].ldw, K = segs.s[si].K;
    for (int k0 = 0; k0 < K; k0 += 32) {
      uint4 av0 = *(const uint4*)&Aseg[(size_t)(rowBase + r0) * lda + k0 + q0 * 8];
      uint4 av1 = *(const uint4*)&Aseg[(size_t)(rowBase + r1) * lda + k0 + q1 * 8];
      uint4 wv0 = *(const uint4*)&Wseg[(size_t)(colBase + r0) * ldw + k0 + q0 * 8];
      uint4 wv1 = *(const uint4*)&Wseg[(size_t)(colBase + r1) * ldw + k0 + q1 * 8];
      __syncthreads();
      *(uint4*)&Asl[c0 * 8] = av0;
      *(uint4*)&Asl[c1 * 8] = av1;
      *(uint4*)&Wsl[c0 * 8] = wv0;
      *(uint4*)&Wsl[c1 * 8] = wv1;
      __syncthreads();
      bf16x8 af[4], bw[4];
#pragma unroll
      for (int i = 0; i < 4; ++i) {
        af[i] = *(bf16x8*)&Asl[(wm * 64 + i * 16 + ml) * 32 + qq * 8];
        bw[i] = *(bf16x8*)&Wsl[(wn * 64 + i * 16 + ml) * 32 + qq * 8];
      }
#pragma unroll
      for (int mf = 0; mf < 4; ++mf)
#pragma unroll
        for (int nf = 0; nf < 4; ++nf)
          acc[mf][nf] = __builtin_amdgcn_mfma_f32_16x16x32_bf16(af[mf], bw[nf], acc[mf][nf], 0, 0, 0);
    }
  }

  if (MODE == 0) {
    unsigned short* dst = (colBase == 0) ? Y : Z;
#pragma unroll
    for (int mf = 0; mf < 4; ++mf) {
      int row = rowBase + wm * 64 + mf * 16 + qq * 4;
#pragma unroll
      for (int nf = 0; nf < 4; ++nf) {
        int col = wn * 64 + nf * 16 + ml;
#pragma unroll
        for (int r = 0; r < 4; ++r)
          dst[(size_t)(row + r) * 128 + col] = f2h(acc[mf][nf][r]);
      }
    }
  } else {
    float bc4[4];
#pragma unroll
    for (int nf = 0; nf < 4; ++nf) bc4[nf] = bias[colBase + wn * 64 + nf * 16 + ml];
#pragma unroll
    for (int mf = 0; mf < 4; ++mf) {
      int row = rowBase + wm * 64 + mf * 16 + qq * 4;
#pragma unroll
      for (int nf = 0; nf < 4; ++nf) {
        int col = colBase + wn * 64 + nf * 16 + ml;
#pragma unroll
        for (int r = 0; r < 4; ++r) {
          float o = fmaxf(acc[mf][nf][r] + bc4[nf], 0.f);
          Ob[(size_t)(row + r) * ldc + col] = f2bf(o);
        }
      }
    }
  }
}

// ---------------- host ----------------
extern "C" void kernel_launch(void* const* d_in, const int* in_sizes, int n_in,
                              void* d_out, int out_size, void* d_ws, size_t ws_size,
                              hipStream_t stream) {
  const float* x      = (const float*)d_in[0];
  const int*   ei     = (const int*)d_in[1];
  const float* Wf_l   = (const float*)d_in[2];
  const float* bf     = (const float*)d_in[3];
  const float* Wf_r   = (const float*)d_in[4];
  const float* W0_l   = (const float*)d_in[5];
  const float* b0     = (const float*)d_in[6];
  const float* W0_r   = (const float*)d_in[7];
  const float* W1_l   = (const float*)d_in[8];
  const float* b1     = (const float*)d_in[9];
  const float* W1_r   = (const float*)d_in[10];
  const float* W_lin  = (const float*)d_in[11];
  const float* b_lin  = (const float*)d_in[12];
  const float* W_lin2 = (const float*)d_in[13];
  const float* b_lin2 = (const float*)d_in[14];
  float* out = (float*)d_out;

  const int N = in_sizes[0] / 64;           // 50000
  const int E = in_sizes[1] / 2;            // 800000
  const int Npad = ((N + 127) / 128) * 128; // 50048
  const int nblkM = Npad / 128;
  const int NB = (N + 63) / 64;             // 782 buckets
  const int G  = 64;                        // partition blocks
  const int CH = (E + G - 1) / G;           // 12500 edges/block
  const int* e_src = ei;
  const int* e_tgt = ei + E;

  size_t off = 0;
  char* base = (char*)d_ws;
  auto carve = [&](size_t bytes) -> void* {
    void* p = base + off;
    off += (bytes + 255) & ~(size_t)255;
    return p;
  };
  int*      row_ptr = (int*)carve((size_t)(N + 1) * 4);
  int*      bcnt    = (int*)carve((size_t)NB * 4);
  int*      boff    = (int*)carve((size_t)(NB + 1) * 4);
  int*      histT   = (int*)carve((size_t)NB * G * 4);
  unsigned* vals    = (unsigned*)carve((size_t)E * 4);
  int*      srcs    = (int*)carve((size_t)E * 4);
  unsigned short* xb    = (unsigned short*)carve((size_t)Npad * 64 * 2);
  unsigned short* xh    = (unsigned short*)carve((size_t)Npad * 64 * 2);
  unsigned short* mb    = (unsigned short*)carve((size_t)Npad * 64 * 2);
  unsigned short* h1b   = (unsigned short*)carve((size_t)Npad * 256 * 2);
  unsigned short* h2b   = (unsigned short*)carve((size_t)Npad * 128 * 2);
  unsigned short* yb    = (unsigned short*)carve((size_t)Npad * 128 * 2);
  unsigned short* zb    = (unsigned short*)carve((size_t)Npad * 128 * 2);
  unsigned short* Wt1hi = (unsigned short*)carve(256 * 128 * 2);
  unsigned short* Wt1lo = (unsigned short*)carve(256 * 128 * 2);
  unsigned short* Wt2hi = (unsigned short*)carve(256 * 256 * 2);
  unsigned short* Wt3hi = (unsigned short*)carve(256 * 128 * 2);
  float* Wcomb = (float*)carve(1024 * 4);
  float* bcomb = (float*)carve(8 * 4);
  (void)ws_size; (void)n_in; (void)out_size;

  const int nbConv = (N * 16 + 255) / 256;  // 3125
  const size_t ldsNB = (size_t)NB * 4;

  // CSR build: radix partition (no global atomics) + per-bucket sort
  hist_k<<<G, 256, ldsNB, stream>>>(e_tgt, histT, E, NB, CH);
  scanb_k<<<(NB + 3) / 4, 256, 0, stream>>>(histT, bcnt, NB);
  bscan_k<<<1, 1024, 0, stream>>>(bcnt, boff, row_ptr, NB, E, N);
  scatter_k<<<G, 256, ldsNB, stream>>>(e_src, e_tgt, boff, histT, vals, E, NB, CH);
  bsort_k<<<NB, 256, 0, stream>>>(vals, boff, row_ptr, srcs, N);

  // merged prep: conv + packs + head fold
  prep_k<<<nbConv + 128 + 256 + 128 + 4, 256, 0, stream>>>(
      x, xb, xh, nbConv, N * 16,
      Wf_l, Wf_r, Wt1hi, Wt1lo,
      W0_l, W0_r, Wt2hi,
      W1_l, W1_r, Wt3hi,
      W_lin, b_lin, W_lin2, b_lin2, Wcomb, bcomb);

  const int nbAgg = (N + 3) / 4;
  const dim3 gemmGrid(nblkM, 2);

  // Layer 1: hi+lo W (4 segs)
  agg_mean64_k<<<nbAgg, 256, 0, stream>>>(xh, row_ptr, srcs, mb, N);
  {
    Segs s;
    s.n = 4;
    s.s[0] = {mb, Wt1hi,      64, 128, 64};
    s.s[1] = {xb, Wt1hi + 64, 64, 128, 64};
    s.s[2] = {mb, Wt1lo,      64, 128, 64};
    s.s[3] = {xb, Wt1lo + 64, 64, 128, 64};
    gemm_mfma_k<1><<<gemmGrid, 256, 0, stream>>>(s, bf, nullptr, nullptr, h1b, 256);
  }

  // Layer 2: hi-only W
  {
    Segs s;
    s.n = 1;
    s.s[0] = {h1b, Wt2hi, 256, 256, 256};
    s.s[1] = {nullptr, nullptr, 0, 0, 0};
    s.s[2] = {nullptr, nullptr, 0, 0, 0};
    s.s[3] = {nullptr, nullptr, 0, 0, 0};
    gemm_mfma_k<0><<<gemmGrid, 256, 0, stream>>>(s, nullptr, yb, zb, nullptr, 256);
  }
  agg128_k<1><<<nbAgg, 256, 0, stream>>>(yb, zb, b0, row_ptr, srcs, h2b, nullptr, nullptr, N);

  // Layer 3 + fused head: hi-only W
  {
    Segs s;
    s.n = 1;
    s.s[0] = {h2b, Wt3hi, 128, 128, 128};
    s.s[1] = {nullptr, nullptr, 0, 0, 0};
    s.s[2] = {nullptr, nullptr, 0, 0, 0};
    s.s[3] = {nullptr, nullptr, 0, 0, 0};
    gemm_mfma_k<0><<<gemmGrid, 256, 0, stream>>>(s, nullptr, yb, zb, nullptr, 256);
  }
  agg128_k<2><<<nbAgg, 256, 0, stream>>>(yb, zb, b1, row_ptr, srcs, out, Wcomb, bcomb, N);
}

// Round 8
// 297.602 us; speedup vs baseline: 1.2039x; 1.2039x over previous
//
#include <hip/hip_runtime.h>
#include <hip/hip_fp16.h>

// GraphSAGE 3-layer + head, MI355X.
// R7: gather lesson learned (R7 bench): multi-row-per-instruction vmem (4 rows
//   per dwordx4) serializes in the address unit AND cut loads-in-flight 8->2:
//   49->111us. REVERTED to one-row-per-instruction (wave-uniform base + lane
//   offset), and killed the serial tail: the last batch issues all 8 loads with
//   clamped indices + wave-uniform 0/1 mask weights -> every batch has 8
//   independent loads in flight. agg64 gathers fp32 x directly (xh dropped).
// CSR: multi-block radix partition (R5). GEMMs: bf16 MFMA 16x16x32, W hi+lo in
// L1, hi-only in L2/L3. Head folded into Wcomb + fused into final agg.

typedef __attribute__((ext_vector_type(8))) short bf16x8;
typedef __attribute__((ext_vector_type(4))) float f32x4;

struct Seg { const unsigned short* A; const unsigned short* W; int lda; int ldw; int K; };
struct Segs { Seg s[4]; int n; };

__device__ __forceinline__ unsigned short f2bf(float x) {
  unsigned u = __float_as_uint(x);
  u += 0x7FFF + ((u >> 16) & 1);   // RNE
  return (unsigned short)(u >> 16);
}
__device__ __forceinline__ unsigned short f2h(float x) {
  return __half_as_ushort(__float2half(x));
}
__device__ __forceinline__ float2 ld_h2(const unsigned short* p, size_t idx) {
  unsigned uv = *(const unsigned*)(p + idx);
  __half2 h = *reinterpret_cast<__half2*>(&uv);
  return __half22float2(h);
}

// ---------------- CSR build: multi-block radix partition ----------------
__global__ __launch_bounds__(256) void hist_k(const int* __restrict__ tgt, int* __restrict__ histT,
                                              int E, int NB, int CH) {
  extern __shared__ int sh[];
  int g = blockIdx.x, tid = threadIdx.x;
  for (int b = tid; b < NB; b += 256) sh[b] = 0;
  __syncthreads();
  int eb = g * CH, ee = min(eb + CH, E);
  for (int i = eb + tid; i < ee; i += 256)
    atomicAdd(&sh[tgt[i] >> 6], 1);
  __syncthreads();
  for (int b = tid; b < NB; b += 256) histT[b * 64 + g] = sh[b];
}

__global__ __launch_bounds__(256) void scanb_k(int* __restrict__ histT, int* __restrict__ bcnt, int NB) {
  int wv = threadIdx.x >> 6, lane = threadIdx.x & 63;
  int b = blockIdx.x * 4 + wv;
  if (b >= NB) return;
  int v = histT[b * 64 + lane];
  int x = v;
#pragma unroll
  for (int o = 1; o < 64; o <<= 1) {
    int y = __shfl_up(x, o);
    if (lane >= o) x += y;
  }
  histT[b * 64 + lane] = x - v;
  if (lane == 63) bcnt[b] = x;
}

__global__ __launch_bounds__(1024) void bscan_k(const int* __restrict__ bcnt, int* __restrict__ boff,
                                                int* __restrict__ row_ptr, int NB, int E, int N) {
  __shared__ int sh[1024];
  int tid = threadIdx.x;
  int v = (tid < NB) ? bcnt[tid] : 0;
  int val = v;
  sh[tid] = val;
  __syncthreads();
  for (int o = 1; o < 1024; o <<= 1) {
    int t = (tid >= o) ? sh[tid - o] : 0;
    __syncthreads();
    val += t;
    sh[tid] = val;
    __syncthreads();
  }
  if (tid < NB) boff[tid] = val - v;
  if (tid == NB - 1) boff[NB] = val;
  if (tid == 0) row_ptr[N] = E;
}

__global__ __launch_bounds__(256) void scatter_k(const int* __restrict__ src, const int* __restrict__ tgt,
                                                 const int* __restrict__ boff, const int* __restrict__ histT,
                                                 unsigned* __restrict__ vals, int E, int NB, int CH) {
  extern __shared__ int sh[];
  int g = blockIdx.x, tid = threadIdx.x;
  for (int b = tid; b < NB; b += 256) sh[b] = boff[b] + histT[b * 64 + g];
  __syncthreads();
  int eb = g * CH, ee = min(eb + CH, E);
  for (int i = eb + tid; i < ee; i += 256) {
    int t = tgt[i], s = src[i];
    int pos = atomicAdd(&sh[t >> 6], 1);
    vals[pos] = (unsigned)s | ((unsigned)(t & 63) << 17);
  }
}

__global__ __launch_bounds__(256) void bsort_k(const unsigned* __restrict__ vals, const int* __restrict__ boff,
                                               int* __restrict__ row_ptr, int* __restrict__ srcs, int N) {
  int b = blockIdx.x;
  int base = b << 6;
  int s0 = boff[b], s1 = boff[b + 1];
  __shared__ int hist[64], excl[64], cur[64];
  int tid = threadIdx.x;
  if (tid < 64) { hist[tid] = 0; cur[tid] = 0; }
  __syncthreads();
  for (int i = s0 + tid; i < s1; i += 256)
    atomicAdd(&hist[(vals[i] >> 17) & 63], 1);
  __syncthreads();
  if (tid < 64) {
    int v = hist[tid];
    int x = v;
#pragma unroll
    for (int o = 1; o < 64; o <<= 1) {
      int y = __shfl_up(x, o);
      if (tid >= o) x += y;
    }
    excl[tid] = x - v;
    int node = base + tid;
    if (node < N) row_ptr[node] = s0 + x - v;
  }
  __syncthreads();
  for (int i = s0 + tid; i < s1; i += 256) {
    unsigned v = vals[i];
    int l = (v >> 17) & 63;
    int pos = s0 + excl[l] + atomicAdd(&cur[l], 1);
    srcs[pos] = (int)(v & 0x1FFFF);
  }
}

// ---------------- merged prep: conv + weight packs + head fold ----------------
__device__ __forceinline__ void split_store(float v, unsigned short* hi, unsigned short* lo, int idx) {
  unsigned short h = f2bf(v);
  float hf = __uint_as_float(((unsigned)h) << 16);
  hi[idx] = h;
  lo[idx] = f2bf(v - hf);
}

__global__ __launch_bounds__(256) void prep_k(
    const float* __restrict__ x, unsigned short* __restrict__ xb, int nbConv, int n4,
    const float* __restrict__ Wf_l, const float* __restrict__ Wf_r,
    unsigned short* __restrict__ Wt1hi, unsigned short* __restrict__ Wt1lo,
    const float* __restrict__ W0_l, const float* __restrict__ W0_r, unsigned short* __restrict__ Wt2hi,
    const float* __restrict__ W1_l, const float* __restrict__ W1_r, unsigned short* __restrict__ Wt3hi,
    const float* __restrict__ Wlin, const float* __restrict__ blin,
    const float* __restrict__ Wlin2, const float* __restrict__ blin2,
    float* __restrict__ Wc, float* __restrict__ bc) {
  int b = blockIdx.x, t = threadIdx.x;
  if (b < nbConv) {
    int i = b * 256 + t;
    if (i < n4) {
      float4 v = ((const float4*)x)[i];
      ((ushort2*)xb)[i * 2]     = make_ushort2(f2bf(v.x), f2bf(v.y));
      ((ushort2*)xb)[i * 2 + 1] = make_ushort2(f2bf(v.z), f2bf(v.w));
    }
    return;
  }
  b -= nbConv;
  if (b < 128) {             // L1 k-split pack, hi+lo: Wt1[n][k] (256 x 128)
    int idx = b * 256 + t;
    int n = idx >> 7, k = idx & 127;
    float v = (k < 64) ? Wf_l[k * 256 + n] : Wf_r[(k - 64) * 256 + n];
    split_store(v, Wt1hi, Wt1lo, idx);
    return;
  }
  b -= 128;
  if (b < 256) {             // L2 n-split pack, hi only: Wt2[n][k] (256 x 256)
    int idx = b * 256 + t;
    int n = idx >> 8, k = idx & 255;
    float v = (n < 128) ? W0_l[k * 128 + n] : W0_r[k * 128 + (n - 128)];
    Wt2hi[idx] = f2bf(v);
    return;
  }
  b -= 256;
  if (b < 128) {             // L3 n-split pack, hi only: Wt3[n][k] (256 x 128)
    int idx = b * 256 + t;
    int n = idx >> 7, k = idx & 127;
    float v = (n < 128) ? W1_l[k * 128 + n] : W1_r[k * 128 + (n - 128)];
    Wt3hi[idx] = f2bf(v);
    return;
  }
  b -= 128;
  {                          // head fold: 4 blocks
    int idx = b * 256 + t;
    if (idx < 1024) {
      int i = idx >> 3, j = idx & 7;
      float acc = 0.f;
      for (int k = 0; k < 128; ++k) acc = fmaf(Wlin[i * 128 + k], Wlin2[k * 8 + j], acc);
      Wc[idx] = acc;
    }
    if (idx < 8) {
      float acc = blin2[idx];
      for (int k = 0; k < 128; ++k) acc = fmaf(blin[k], Wlin2[k * 8 + idx], acc);
      bc[idx] = acc;
    }
  }
}

// ---------------- aggregation ----------------
// wave per node, D=64, lane=dim (fp32 gather from x). All batches 8 loads in
// flight; final batch uses clamped indices + wave-uniform masks (no serial tail).
__global__ __launch_bounds__(256) void agg_mean64_k(const float* __restrict__ x, const int* __restrict__ rp,
                                                    const int* __restrict__ srcs, unsigned short* __restrict__ mb, int n) {
  int w = threadIdx.x >> 6, lane = threadIdx.x & 63;
  int node = blockIdx.x * 4 + w;
  if (node >= n) return;
  int s0 = rp[node], s1 = rp[node + 1];
  float sum = 0.f;
  int e = s0;
  for (; e + 8 <= s1; e += 8) {
    int i0 = srcs[e], i1 = srcs[e + 1], i2 = srcs[e + 2], i3 = srcs[e + 3];
    int i4 = srcs[e + 4], i5 = srcs[e + 5], i6 = srcs[e + 6], i7 = srcs[e + 7];
    float v0 = x[(size_t)i0 * 64 + lane], v1 = x[(size_t)i1 * 64 + lane];
    float v2 = x[(size_t)i2 * 64 + lane], v3 = x[(size_t)i3 * 64 + lane];
    float v4 = x[(size_t)i4 * 64 + lane], v5 = x[(size_t)i5 * 64 + lane];
    float v6 = x[(size_t)i6 * 64 + lane], v7 = x[(size_t)i7 * 64 + lane];
    sum += ((v0 + v1) + (v2 + v3)) + ((v4 + v5) + (v6 + v7));
  }
  int rem = s1 - e;
  if (rem > 0) {
    int last = s1 - 1;
    int i0 = srcs[e];
    int i1 = srcs[min(e + 1, last)], i2 = srcs[min(e + 2, last)], i3 = srcs[min(e + 3, last)];
    int i4 = srcs[min(e + 4, last)], i5 = srcs[min(e + 5, last)], i6 = srcs[min(e + 6, last)];
    float v0 = x[(size_t)i0 * 64 + lane], v1 = x[(size_t)i1 * 64 + lane];
    float v2 = x[(size_t)i2 * 64 + lane], v3 = x[(size_t)i3 * 64 + lane];
    float v4 = x[(size_t)i4 * 64 + lane], v5 = x[(size_t)i5 * 64 + lane];
    float v6 = x[(size_t)i6 * 64 + lane];
    float m1 = (rem > 1) ? 1.f : 0.f, m2 = (rem > 2) ? 1.f : 0.f, m3 = (rem > 3) ? 1.f : 0.f;
    float m4 = (rem > 4) ? 1.f : 0.f, m5 = (rem > 5) ? 1.f : 0.f, m6 = (rem > 6) ? 1.f : 0.f;
    sum += v0;
    sum = fmaf(m1, v1, sum); sum = fmaf(m2, v2, sum); sum = fmaf(m3, v3, sum);
    sum = fmaf(m4, v4, sum); sum = fmaf(m5, v5, sum); sum = fmaf(m6, v6, sum);
  }
  int deg = s1 - s0;
  float inv = 1.f / (float)(deg > 0 ? deg : 1);
  mb[(size_t)node * 64 + lane] = f2bf(sum * inv);
}

// wave per node, D=128, lane = 2 dims (fp16 gather, one row per instruction).
// OUTMODE 1: hout = bf16 h (N x 128). OUTMODE 2: fused head -> out fp32 (N x 8).
template <int OUTMODE>
__global__ __launch_bounds__(256) void agg128_k(const unsigned short* __restrict__ yb,
                                                const unsigned short* __restrict__ zb,
                                                const float* __restrict__ bias,
                                                const int* __restrict__ rp, const int* __restrict__ srcs,
                                                void* __restrict__ hout,
                                                const float* __restrict__ Wc, const float* __restrict__ bc, int n) {
  int w = threadIdx.x >> 6, lane = threadIdx.x & 63;
  int node = blockIdx.x * 4 + w;
  if (node >= n) return;
  int s0 = rp[node], s1 = rp[node + 1];
  int d = lane * 2;
  float sx = 0.f, sy = 0.f;
  int e = s0;
  for (; e + 8 <= s1; e += 8) {
    int i0 = srcs[e], i1 = srcs[e + 1], i2 = srcs[e + 2], i3 = srcs[e + 3];
    int i4 = srcs[e + 4], i5 = srcs[e + 5], i6 = srcs[e + 6], i7 = srcs[e + 7];
    float2 v0 = ld_h2(yb, (size_t)i0 * 128 + d);
    float2 v1 = ld_h2(yb, (size_t)i1 * 128 + d);
    float2 v2 = ld_h2(yb, (size_t)i2 * 128 + d);
    float2 v3 = ld_h2(yb, (size_t)i3 * 128 + d);
    float2 v4 = ld_h2(yb, (size_t)i4 * 128 + d);
    float2 v5 = ld_h2(yb, (size_t)i5 * 128 + d);
    float2 v6 = ld_h2(yb, (size_t)i6 * 128 + d);
    float2 v7 = ld_h2(yb, (size_t)i7 * 128 + d);
    sx += ((v0.x + v1.x) + (v2.x + v3.x)) + ((v4.x + v5.x) + (v6.x + v7.x));
    sy += ((v0.y + v1.y) + (v2.y + v3.y)) + ((v4.y + v5.y) + (v6.y + v7.y));
  }
  int rem = s1 - e;
  if (rem > 0) {
    int last = s1 - 1;
    int i0 = srcs[e];
    int i1 = srcs[min(e + 1, last)], i2 = srcs[min(e + 2, last)], i3 = srcs[min(e + 3, last)];
    int i4 = srcs[min(e + 4, last)], i5 = srcs[min(e + 5, last)], i6 = srcs[min(e + 6, last)];
    float2 v0 = ld_h2(yb, (size_t)i0 * 128 + d);
    float2 v1 = ld_h2(yb, (size_t)i1 * 128 + d);
    float2 v2 = ld_h2(yb, (size_t)i2 * 128 + d);
    float2 v3 = ld_h2(yb, (size_t)i3 * 128 + d);
    float2 v4 = ld_h2(yb, (size_t)i4 * 128 + d);
    float2 v5 = ld_h2(yb, (size_t)i5 * 128 + d);
    float2 v6 = ld_h2(yb, (size_t)i6 * 128 + d);
    float m1 = (rem > 1) ? 1.f : 0.f, m2 = (rem > 2) ? 1.f : 0.f, m3 = (rem > 3) ? 1.f : 0.f;
    float m4 = (rem > 4) ? 1.f : 0.f, m5 = (rem > 5) ? 1.f : 0.f, m6 = (rem > 6) ? 1.f : 0.f;
    sx += v0.x; sy += v0.y;
    sx = fmaf(m1, v1.x, sx); sy = fmaf(m1, v1.y, sy);
    sx = fmaf(m2, v2.x, sx); sy = fmaf(m2, v2.y, sy);
    sx = fmaf(m3, v3.x, sx); sy = fmaf(m3, v3.y, sy);
    sx = fmaf(m4, v4.x, sx); sy = fmaf(m4, v4.y, sy);
    sx = fmaf(m5, v5.x, sx); sy = fmaf(m5, v5.y, sy);
    sx = fmaf(m6, v6.x, sx); sy = fmaf(m6, v6.y, sy);
  }
  int deg = s1 - s0;
  float inv = 1.f / (float)(deg > 0 ? deg : 1);
  float2 z = ld_h2(zb, (size_t)node * 128 + d);
  float2 b2 = *(const float2*)&bias[d];
  float ox = fmaxf(fmaf(sx, inv, z.x + b2.x), 0.f);
  float oy = fmaxf(fmaf(sy, inv, z.y + b2.y), 0.f);

  if (OUTMODE == 1) {
    ((ushort2*)hout)[((size_t)node * 128 + d) / 2] = make_ushort2(f2bf(ox), f2bf(oy));
  } else {
    // fused head: out[node][j] = sum_d o_d * Wc[d][j] + bc[j]
    const float4* wr = (const float4*)&Wc[d * 8];   // rows d, d+1 (16 floats), L1-hot
    float4 wa0 = wr[0], wa1 = wr[1], wb0 = wr[2], wb1 = wr[3];
    float a8[8];
    a8[0] = ox * wa0.x + oy * wb0.x;
    a8[1] = ox * wa0.y + oy * wb0.y;
    a8[2] = ox * wa0.z + oy * wb0.z;
    a8[3] = ox * wa0.w + oy * wb0.w;
    a8[4] = ox * wa1.x + oy * wb1.x;
    a8[5] = ox * wa1.y + oy * wb1.y;
    a8[6] = ox * wa1.z + oy * wb1.z;
    a8[7] = ox * wa1.w + oy * wb1.w;
#pragma unroll
    for (int off = 32; off >= 1; off >>= 1) {
#pragma unroll
      for (int j = 0; j < 8; ++j) a8[j] += __shfl_xor(a8[j], off);
    }
    if (lane == 0) {
      float* o = (float*)hout + (size_t)node * 8;
      *(float4*)o       = make_float4(a8[0] + bc[0], a8[1] + bc[1], a8[2] + bc[2], a8[3] + bc[3]);
      *(float4*)(o + 4) = make_float4(a8[4] + bc[4], a8[5] + bc[5], a8[6] + bc[6], a8[7] + bc[7]);
    }
  }
}

// ---------------- MFMA GEMM ----------------
// Block tile 128x128, 4 waves (2x2), each wave 64x64 via 4x4 frags of 16x16x32 bf16 MFMA.
// MODE 0: fp16 out, split into Y (cols 0..127) / Z (cols 128..255), ld 128.
// MODE 1: bias+relu -> bf16 out Ob (ldc 256).
template <int MODE>
__global__ __launch_bounds__(256) void gemm_mfma_k(Segs segs, const float* __restrict__ bias,
                                                   unsigned short* __restrict__ Y, unsigned short* __restrict__ Z,
                                                   unsigned short* __restrict__ Ob, int ldc) {
  __shared__ unsigned short Asl[128 * 32];
  __shared__ unsigned short Wsl[128 * 32];
  int tid = threadIdx.x;
  int lane = tid & 63, wave = tid >> 6;
  int wm = wave & 1, wn = wave >> 1;
  int rowBase = blockIdx.x * 128, colBase = blockIdx.y * 128;
  f32x4 acc[4][4] = {};

  int c0 = tid, c1 = tid + 256;
  int r0 = c0 >> 2, q0 = c0 & 3;
  int r1 = c1 >> 2, q1 = c1 & 3;
  int ml = lane & 15, qq = lane >> 4;

  for (int si = 0; si < segs.n; ++si) {
    const unsigned short* Aseg = segs.s[si].A;
    const unsigned short* Wseg = segs.s[si].W;
    int lda = segs.s[si].lda, ldw = segs.s[si].ldw, K = segs.s[si].K;
    for (int k0 = 0; k0 < K; k0 += 32) {
      uint4 av0 = *(const uint4*)&Aseg[(size_t)(rowBase + r0) * lda + k0 + q0 * 8];
      uint4 av1 = *(const uint4*)&Aseg[(size_t)(rowBase + r1) * lda + k0 + q1 * 8];
      uint4 wv0 = *(const uint4*)&Wseg[(size_t)(colBase + r0) * ldw + k0 + q0 * 8];
      uint4 wv1 = *(const uint4*)&Wseg[(size_t)(colBase + r1) * ldw + k0 + q1 * 8];
      __syncthreads();
      *(uint4*)&Asl[c0 * 8] = av0;
      *(uint4*)&Asl[c1 * 8] = av1;
      *(uint4*)&Wsl[c0 * 8] = wv0;
      *(uint4*)&Wsl[c1 * 8] = wv1;
      __syncthreads();
      bf16x8 af[4], bw[4];
#pragma unroll
      for (int i = 0; i < 4; ++i) {
        af[i] = *(bf16x8*)&Asl[(wm * 64 + i * 16 + ml) * 32 + qq * 8];
        bw[i] = *(bf16x8*)&Wsl[(wn * 64 + i * 16 + ml) * 32 + qq * 8];
      }
#pragma unroll
      for (int mf = 0; mf < 4; ++mf)
#pragma unroll
        for (int nf = 0; nf < 4; ++nf)
          acc[mf][nf] = __builtin_amdgcn_mfma_f32_16x16x32_bf16(af[mf], bw[nf], acc[mf][nf], 0, 0, 0);
    }
  }

  if (MODE == 0) {
    unsigned short* dst = (colBase == 0) ? Y : Z;
#pragma unroll
    for (int mf = 0; mf < 4; ++mf) {
      int row = rowBase + wm * 64 + mf * 16 + qq * 4;
#pragma unroll
      for (int nf = 0; nf < 4; ++nf) {
        int col = wn * 64 + nf * 16 + ml;
#pragma unroll
        for (int r = 0; r < 4; ++r)
          dst[(size_t)(row + r) * 128 + col] = f2h(acc[mf][nf][r]);
      }
    }
  } else {
    float bc4[4];
#pragma unroll
    for (int nf = 0; nf < 4; ++nf) bc4[nf] = bias[colBase + wn * 64 + nf * 16 + ml];
#pragma unroll
    for (int mf = 0; mf < 4; ++mf) {
      int row = rowBase + wm * 64 + mf * 16 + qq * 4;
#pragma unroll
      for (int nf = 0; nf < 4; ++nf) {
        int col = colBase + wn * 64 + nf * 16 + ml;
#pragma unroll
        for (int r = 0; r < 4; ++r) {
          float o = fmaxf(acc[mf][nf][r] + bc4[nf], 0.f);
          Ob[(size_t)(row + r) * ldc + col] = f2bf(o);
        }
      }
    }
  }
}

// ---------------- host ----------------
extern "C" void kernel_launch(void* const* d_in, const int* in_sizes, int n_in,
                              void* d_out, int out_size, void* d_ws, size_t ws_size,
                              hipStream_t stream) {
  const float* x      = (const float*)d_in[0];
  const int*   ei     = (const int*)d_in[1];
  const float* Wf_l   = (const float*)d_in[2];
  const float* bf     = (const float*)d_in[3];
  const float* Wf_r   = (const float*)d_in[4];
  const float* W0_l   = (const float*)d_in[5];
  const float* b0     = (const float*)d_in[6];
  const float* W0_r   = (const float*)d_in[7];
  const float* W1_l   = (const float*)d_in[8];
  const float* b1     = (const float*)d_in[9];
  const float* W1_r   = (const float*)d_in[10];
  const float* W_lin  = (const float*)d_in[11];
  const float* b_lin  = (const float*)d_in[12];
  const float* W_lin2 = (const float*)d_in[13];
  const float* b_lin2 = (const float*)d_in[14];
  float* out = (float*)d_out;

  const int N = in_sizes[0] / 64;           // 50000
  const int E = in_sizes[1] / 2;            // 800000
  const int Npad = ((N + 127) / 128) * 128; // 50048
  const int nblkM = Npad / 128;
  const int NB = (N + 63) / 64;             // 782 buckets
  const int G  = 64;                        // partition blocks
  const int CH = (E + G - 1) / G;           // 12500 edges/block
  const int* e_src = ei;
  const int* e_tgt = ei + E;

  size_t off = 0;
  char* base = (char*)d_ws;
  auto carve = [&](size_t bytes) -> void* {
    void* p = base + off;
    off += (bytes + 255) & ~(size_t)255;
    return p;
  };
  int*      row_ptr = (int*)carve((size_t)(N + 1) * 4);
  int*      bcnt    = (int*)carve((size_t)NB * 4);
  int*      boff    = (int*)carve((size_t)(NB + 1) * 4);
  int*      histT   = (int*)carve((size_t)NB * G * 4);
  unsigned* vals    = (unsigned*)carve((size_t)E * 4);
  int*      srcs    = (int*)carve((size_t)E * 4);
  unsigned short* xb    = (unsigned short*)carve((size_t)Npad * 64 * 2);
  unsigned short* mb    = (unsigned short*)carve((size_t)Npad * 64 * 2);
  unsigned short* h1b   = (unsigned short*)carve((size_t)Npad * 256 * 2);
  unsigned short* h2b   = (unsigned short*)carve((size_t)Npad * 128 * 2);
  unsigned short* yb    = (unsigned short*)carve((size_t)Npad * 128 * 2);
  unsigned short* zb    = (unsigned short*)carve((size_t)Npad * 128 * 2);
  unsigned short* Wt1hi = (unsigned short*)carve(256 * 128 * 2);
  unsigned short* Wt1lo = (unsigned short*)carve(256 * 128 * 2);
  unsigned short* Wt2hi = (unsigned short*)carve(256 * 256 * 2);
  unsigned short* Wt3hi = (unsigned short*)carve(256 * 128 * 2);
  float* Wcomb = (float*)carve(1024 * 4);
  float* bcomb = (float*)carve(8 * 4);
  (void)ws_size; (void)n_in; (void)out_size;

  const int nbConv = (N * 16 + 255) / 256;  // 3125
  const size_t ldsNB = (size_t)NB * 4;

  // CSR build: radix partition (no global atomics) + per-bucket sort
  hist_k<<<G, 256, ldsNB, stream>>>(e_tgt, histT, E, NB, CH);
  scanb_k<<<(NB + 3) / 4, 256, 0, stream>>>(histT, bcnt, NB);
  bscan_k<<<1, 1024, 0, stream>>>(bcnt, boff, row_ptr, NB, E, N);
  scatter_k<<<G, 256, ldsNB, stream>>>(e_src, e_tgt, boff, histT, vals, E, NB, CH);
  bsort_k<<<NB, 256, 0, stream>>>(vals, boff, row_ptr, srcs, N);

  // merged prep: conv + packs + head fold
  prep_k<<<nbConv + 128 + 256 + 128 + 4, 256, 0, stream>>>(
      x, xb, nbConv, N * 16,
      Wf_l, Wf_r, Wt1hi, Wt1lo,
      W0_l, W0_r, Wt2hi,
      W1_l, W1_r, Wt3hi,
      W_lin, b_lin, W_lin2, b_lin2, Wcomb, bcomb);

  const int nbAgg = (N + 3) / 4;
  const dim3 gemmGrid(nblkM, 2);

  // Layer 1: hi+lo W (4 segs)
  agg_mean64_k<<<nbAgg, 256, 0, stream>>>(x, row_ptr, srcs, mb, N);
  {
    Segs s;
    s.n = 4;
    s.s[0] = {mb, Wt1hi,      64, 128, 64};
    s.s[1] = {xb, Wt1hi + 64, 64, 128, 64};
    s.s[2] = {mb, Wt1lo,      64, 128, 64};
    s.s[3] = {xb, Wt1lo + 64, 64, 128, 64};
    gemm_mfma_k<1><<<gemmGrid, 256, 0, stream>>>(s, bf, nullptr, nullptr, h1b, 256);
  }

  // Layer 2: hi-only W
  {
    Segs s;
    s.n = 1;
    s.s[0] = {h1b, Wt2hi, 256, 256, 256};
    s.s[1] = {nullptr, nullptr, 0, 0, 0};
    s.s[2] = {nullptr, nullptr, 0, 0, 0};
    s.s[3] = {nullptr, nullptr, 0, 0, 0};
    gemm_mfma_k<0><<<gemmGrid, 256, 0, stream>>>(s, nullptr, yb, zb, nullptr, 256);
  }
  agg128_k<1><<<nbAgg, 256, 0, stream>>>(yb, zb, b0, row_ptr, srcs, h2b, nullptr, nullptr, N);

  // Layer 3 + fused head: hi-only W
  {
    Segs s;
    s.n = 1;
    s.s[0] = {h2b, Wt3hi, 128, 128, 128};
    s.s[1] = {nullptr, nullptr, 0, 0, 0};
    s.s[2] = {nullptr, nullptr, 0, 0, 0};
    s.s[3] = {nullptr, nullptr, 0, 0, 0};
    gemm_mfma_k<0><<<gemmGrid, 256, 0, stream>>>(s, nullptr, yb, zb, nullptr, 256);
  }
  agg128_k<2><<<nbAgg, 256, 0, stream>>>(yb, zb, b1, row_ptr, srcs, out, Wcomb, bcomb, N);
}

// Round 9
// 283.647 us; speedup vs baseline: 1.2631x; 1.0492x over previous
//
#include <hip/hip_runtime.h>
#include <hip/hip_fp16.h>

// GraphSAGE 3-layer + head, MI355X.
// R8 -> R9:
//   - L1 weights hi-only (R4 evidence: dropping W-lo in L2/L3 left absmax
//     bit-identical; A-side bf16 dominates). GEMM1 segs 4 -> 2.
//   - aggs unrolled to 16 loads in flight (deg~16 => one parallel batch,
//     masked clamped tail, dup loads hit L1).
//   - removed dead memset; bsort+prep merged into one launch.
// Gather law (R7): one row per vmem instruction (wave-uniform base + lane
// offset); multi-row instructions serialize in the address unit.

typedef __attribute__((ext_vector_type(8))) short bf16x8;
typedef __attribute__((ext_vector_type(4))) float f32x4;

struct Seg { const unsigned short* A; const unsigned short* W; int lda; int ldw; int K; };
struct Segs { Seg s[4]; int n; };

__device__ __forceinline__ unsigned short f2bf(float x) {
  unsigned u = __float_as_uint(x);
  u += 0x7FFF + ((u >> 16) & 1);   // RNE
  return (unsigned short)(u >> 16);
}
__device__ __forceinline__ unsigned short f2h(float x) {
  return __half_as_ushort(__float2half(x));
}
__device__ __forceinline__ float2 ld_h2(const unsigned short* p, size_t idx) {
  unsigned uv = *(const unsigned*)(p + idx);
  __half2 h = *reinterpret_cast<__half2*>(&uv);
  return __half22float2(h);
}

// ---------------- CSR build: multi-block radix partition ----------------
__global__ __launch_bounds__(256) void hist_k(const int* __restrict__ tgt, int* __restrict__ histT,
                                              int E, int NB, int CH) {
  extern __shared__ int sh[];
  int g = blockIdx.x, tid = threadIdx.x;
  for (int b = tid; b < NB; b += 256) sh[b] = 0;
  __syncthreads();
  int eb = g * CH, ee = min(eb + CH, E);
  for (int i = eb + tid; i < ee; i += 256)
    atomicAdd(&sh[tgt[i] >> 6], 1);
  __syncthreads();
  for (int b = tid; b < NB; b += 256) histT[b * 64 + g] = sh[b];
}

__global__ __launch_bounds__(256) void scanb_k(int* __restrict__ histT, int* __restrict__ bcnt, int NB) {
  int wv = threadIdx.x >> 6, lane = threadIdx.x & 63;
  int b = blockIdx.x * 4 + wv;
  if (b >= NB) return;
  int v = histT[b * 64 + lane];
  int x = v;
#pragma unroll
  for (int o = 1; o < 64; o <<= 1) {
    int y = __shfl_up(x, o);
    if (lane >= o) x += y;
  }
  histT[b * 64 + lane] = x - v;
  if (lane == 63) bcnt[b] = x;
}

__global__ __launch_bounds__(1024) void bscan_k(const int* __restrict__ bcnt, int* __restrict__ boff,
                                                int* __restrict__ row_ptr, int NB, int E, int N) {
  __shared__ int sh[1024];
  int tid = threadIdx.x;
  int v = (tid < NB) ? bcnt[tid] : 0;
  int val = v;
  sh[tid] = val;
  __syncthreads();
  for (int o = 1; o < 1024; o <<= 1) {
    int t = (tid >= o) ? sh[tid - o] : 0;
    __syncthreads();
    val += t;
    sh[tid] = val;
    __syncthreads();
  }
  if (tid < NB) boff[tid] = val - v;
  if (tid == NB - 1) boff[NB] = val;
  if (tid == 0) row_ptr[N] = E;
}

__global__ __launch_bounds__(256) void scatter_k(const int* __restrict__ src, const int* __restrict__ tgt,
                                                 const int* __restrict__ boff, const int* __restrict__ histT,
                                                 unsigned* __restrict__ vals, int E, int NB, int CH) {
  extern __shared__ int sh[];
  int g = blockIdx.x, tid = threadIdx.x;
  for (int b = tid; b < NB; b += 256) sh[b] = boff[b] + histT[b * 64 + g];
  __syncthreads();
  int eb = g * CH, ee = min(eb + CH, E);
  for (int i = eb + tid; i < ee; i += 256) {
    int t = tgt[i], s = src[i];
    int pos = atomicAdd(&sh[t >> 6], 1);
    vals[pos] = (unsigned)s | ((unsigned)(t & 63) << 17);
  }
}

// ---------------- merged: per-bucket sort + prep (conv/packs/head fold) ----------------
__global__ __launch_bounds__(256) void bsort_prep_k(
    const unsigned* __restrict__ vals, const int* __restrict__ boff,
    int* __restrict__ row_ptr, int* __restrict__ srcs, int N, int NB,
    const float* __restrict__ x, unsigned short* __restrict__ xb, int nbConv, int n4,
    const float* __restrict__ Wf_l, const float* __restrict__ Wf_r, unsigned short* __restrict__ Wt1hi,
    const float* __restrict__ W0_l, const float* __restrict__ W0_r, unsigned short* __restrict__ Wt2hi,
    const float* __restrict__ W1_l, const float* __restrict__ W1_r, unsigned short* __restrict__ Wt3hi,
    const float* __restrict__ Wlin, const float* __restrict__ blin,
    const float* __restrict__ Wlin2, const float* __restrict__ blin2,
    float* __restrict__ Wc, float* __restrict__ bc) {
  int b = blockIdx.x, tid = threadIdx.x;
  if (b < NB) {                      // ---- bsort part ----
    int base = b << 6;
    int s0 = boff[b], s1 = boff[b + 1];
    __shared__ int hist[64], excl[64], cur[64];
    if (tid < 64) { hist[tid] = 0; cur[tid] = 0; }
    __syncthreads();
    for (int i = s0 + tid; i < s1; i += 256)
      atomicAdd(&hist[(vals[i] >> 17) & 63], 1);
    __syncthreads();
    if (tid < 64) {
      int v = hist[tid];
      int xx = v;
#pragma unroll
      for (int o = 1; o < 64; o <<= 1) {
        int y = __shfl_up(xx, o);
        if (tid >= o) xx += y;
      }
      excl[tid] = xx - v;
      int node = base + tid;
      if (node < N) row_ptr[node] = s0 + xx - v;
    }
    __syncthreads();
    for (int i = s0 + tid; i < s1; i += 256) {
      unsigned v = vals[i];
      int l = (v >> 17) & 63;
      int pos = s0 + excl[l] + atomicAdd(&cur[l], 1);
      srcs[pos] = (int)(v & 0x1FFFF);
    }
    return;
  }
  b -= NB;                           // ---- prep part ----
  if (b < nbConv) {
    int i = b * 256 + tid;
    if (i < n4) {
      float4 v = ((const float4*)x)[i];
      ((ushort2*)xb)[i * 2]     = make_ushort2(f2bf(v.x), f2bf(v.y));
      ((ushort2*)xb)[i * 2 + 1] = make_ushort2(f2bf(v.z), f2bf(v.w));
    }
    return;
  }
  b -= nbConv;
  if (b < 128) {             // L1 k-split pack, hi only: Wt1[n][k] (256 x 128)
    int idx = b * 256 + tid;
    int n = idx >> 7, k = idx & 127;
    float v = (k < 64) ? Wf_l[k * 256 + n] : Wf_r[(k - 64) * 256 + n];
    Wt1hi[idx] = f2bf(v);
    return;
  }
  b -= 128;
  if (b < 256) {             // L2 n-split pack: Wt2[n][k] (256 x 256)
    int idx = b * 256 + tid;
    int n = idx >> 8, k = idx & 255;
    float v = (n < 128) ? W0_l[k * 128 + n] : W0_r[k * 128 + (n - 128)];
    Wt2hi[idx] = f2bf(v);
    return;
  }
  b -= 256;
  if (b < 128) {             // L3 n-split pack: Wt3[n][k] (256 x 128)
    int idx = b * 256 + tid;
    int n = idx >> 7, k = idx & 127;
    float v = (n < 128) ? W1_l[k * 128 + n] : W1_r[k * 128 + (n - 128)];
    Wt3hi[idx] = f2bf(v);
    return;
  }
  b -= 128;
  {                          // head fold: 4 blocks
    int idx = b * 256 + tid;
    if (idx < 1024) {
      int i = idx >> 3, j = idx & 7;
      float acc = 0.f;
      for (int k = 0; k < 128; ++k) acc = fmaf(Wlin[i * 128 + k], Wlin2[k * 8 + j], acc);
      Wc[idx] = acc;
    }
    if (idx < 8) {
      float acc = blin2[idx];
      for (int k = 0; k < 128; ++k) acc = fmaf(blin[k], Wlin2[k * 8 + idx], acc);
      bc[idx] = acc;
    }
  }
}

// ---------------- aggregation ----------------
// wave per node, D=64, lane=dim, fp32 gather from x; 16 loads in flight,
// masked clamped tail (dups are L1 hits).
__global__ __launch_bounds__(256) void agg_mean64_k(const float* __restrict__ x, const int* __restrict__ rp,
                                                    const int* __restrict__ srcs, unsigned short* __restrict__ mb, int n) {
  int w = threadIdx.x >> 6, lane = threadIdx.x & 63;
  int node = blockIdx.x * 4 + w;
  if (node >= n) return;
  int s0 = rp[node], s1 = rp[node + 1];
  float sum = 0.f;
  int e = s0;
  for (; e + 16 <= s1; e += 16) {
    int idx[16];
#pragma unroll
    for (int i = 0; i < 16; ++i) idx[i] = srcs[e + i];
    float v[16];
#pragma unroll
    for (int i = 0; i < 16; ++i) v[i] = x[(size_t)idx[i] * 64 + lane];
    float t0 = ((v[0] + v[1]) + (v[2] + v[3])) + ((v[4] + v[5]) + (v[6] + v[7]));
    float t1 = ((v[8] + v[9]) + (v[10] + v[11])) + ((v[12] + v[13]) + (v[14] + v[15]));
    sum += t0 + t1;
  }
  int rem = s1 - e;
  if (rem > 0) {
    int last = s1 - 1;
    int idx[16];
    idx[0] = srcs[e];
#pragma unroll
    for (int i = 1; i < 16; ++i) idx[i] = srcs[min(e + i, last)];
    float v[16];
#pragma unroll
    for (int i = 0; i < 16; ++i) v[i] = x[(size_t)idx[i] * 64 + lane];
    sum += v[0];
#pragma unroll
    for (int i = 1; i < 16; ++i) {
      float m = (rem > i) ? 1.f : 0.f;
      sum = fmaf(m, v[i], sum);
    }
  }
  int deg = s1 - s0;
  float inv = 1.f / (float)(deg > 0 ? deg : 1);
  mb[(size_t)node * 64 + lane] = f2bf(sum * inv);
}

// wave per node, D=128, lane = 2 dims, fp16 gather; 16 loads in flight, masked tail.
// OUTMODE 1: hout = bf16 h (N x 128). OUTMODE 2: fused head -> out fp32 (N x 8).
template <int OUTMODE>
__global__ __launch_bounds__(256) void agg128_k(const unsigned short* __restrict__ yb,
                                                const unsigned short* __restrict__ zb,
                                                const float* __restrict__ bias,
                                                const int* __restrict__ rp, const int* __restrict__ srcs,
                                                void* __restrict__ hout,
                                                const float* __restrict__ Wc, const float* __restrict__ bc, int n) {
  int w = threadIdx.x >> 6, lane = threadIdx.x & 63;
  int node = blockIdx.x * 4 + w;
  if (node >= n) return;
  int s0 = rp[node], s1 = rp[node + 1];
  int d = lane * 2;
  float sx = 0.f, sy = 0.f;
  int e = s0;
  for (; e + 16 <= s1; e += 16) {
    int idx[16];
#pragma unroll
    for (int i = 0; i < 16; ++i) idx[i] = srcs[e + i];
    float2 v[16];
#pragma unroll
    for (int i = 0; i < 16; ++i) v[i] = ld_h2(yb, (size_t)idx[i] * 128 + d);
    float tx0 = ((v[0].x + v[1].x) + (v[2].x + v[3].x)) + ((v[4].x + v[5].x) + (v[6].x + v[7].x));
    float tx1 = ((v[8].x + v[9].x) + (v[10].x + v[11].x)) + ((v[12].x + v[13].x) + (v[14].x + v[15].x));
    float ty0 = ((v[0].y + v[1].y) + (v[2].y + v[3].y)) + ((v[4].y + v[5].y) + (v[6].y + v[7].y));
    float ty1 = ((v[8].y + v[9].y) + (v[10].y + v[11].y)) + ((v[12].y + v[13].y) + (v[14].y + v[15].y));
    sx += tx0 + tx1;
    sy += ty0 + ty1;
  }
  int rem = s1 - e;
  if (rem > 0) {
    int last = s1 - 1;
    int idx[16];
    idx[0] = srcs[e];
#pragma unroll
    for (int i = 1; i < 16; ++i) idx[i] = srcs[min(e + i, last)];
    float2 v[16];
#pragma unroll
    for (int i = 0; i < 16; ++i) v[i] = ld_h2(yb, (size_t)idx[i] * 128 + d);
    sx += v[0].x; sy += v[0].y;
#pragma unroll
    for (int i = 1; i < 16; ++i) {
      float m = (rem > i) ? 1.f : 0.f;
      sx = fmaf(m, v[i].x, sx);
      sy = fmaf(m, v[i].y, sy);
    }
  }
  int deg = s1 - s0;
  float inv = 1.f / (float)(deg > 0 ? deg : 1);
  float2 z = ld_h2(zb, (size_t)node * 128 + d);
  float2 b2 = *(const float2*)&bias[d];
  float ox = fmaxf(fmaf(sx, inv, z.x + b2.x), 0.f);
  float oy = fmaxf(fmaf(sy, inv, z.y + b2.y), 0.f);

  if (OUTMODE == 1) {
    ((ushort2*)hout)[((size_t)node * 128 + d) / 2] = make_ushort2(f2bf(ox), f2bf(oy));
  } else {
    // fused head: out[node][j] = sum_d o_d * Wc[d][j] + bc[j]
    const float4* wr = (const float4*)&Wc[d * 8];
    float4 wa0 = wr[0], wa1 = wr[1], wb0 = wr[2], wb1 = wr[3];
    float a8[8];
    a8[0] = ox * wa0.x + oy * wb0.x;
    a8[1] = ox * wa0.y + oy * wb0.y;
    a8[2] = ox * wa0.z + oy * wb0.z;
    a8[3] = ox * wa0.w + oy * wb0.w;
    a8[4] = ox * wa1.x + oy * wb1.x;
    a8[5] = ox * wa1.y + oy * wb1.y;
    a8[6] = ox * wa1.z + oy * wb1.z;
    a8[7] = ox * wa1.w + oy * wb1.w;
#pragma unroll
    for (int off = 32; off >= 1; off >>= 1) {
#pragma unroll
      for (int j = 0; j < 8; ++j) a8[j] += __shfl_xor(a8[j], off);
    }
    if (lane == 0) {
      float* o = (float*)hout + (size_t)node * 8;
      *(float4*)o       = make_float4(a8[0] + bc[0], a8[1] + bc[1], a8[2] + bc[2], a8[3] + bc[3]);
      *(float4*)(o + 4) = make_float4(a8[4] + bc[4], a8[5] + bc[5], a8[6] + bc[6], a8[7] + bc[7]);
    }
  }
}

// ---------------- MFMA GEMM ----------------
// Block tile 128x128, 4 waves (2x2), each wave 64x64 via 4x4 frags of 16x16x32 bf16 MFMA.
// MODE 0: fp16 out, split into Y (cols 0..127) / Z (cols 128..255), ld 128.
// MODE 1: bias+relu -> bf16 out Ob (ldc 256).
template <int MODE>
__global__ __launch_bounds__(256) void gemm_mfma_k(Segs segs, const float* __restrict__ bias,
                                                   unsigned short* __restrict__ Y, unsigned short* __restrict__ Z,
                                                   unsigned short* __restrict__ Ob, int ldc) {
  __shared__ unsigned short Asl[128 * 32];
  __shared__ unsigned short Wsl[128 * 32];
  int tid = threadIdx.x;
  int lane = tid & 63, wave = tid >> 6;
  int wm = wave & 1, wn = wave >> 1;
  int rowBase = blockIdx.x * 128, colBase = blockIdx.y * 128;
  f32x4 acc[4][4] = {};

  int c0 = tid, c1 = tid + 256;
  int r0 = c0 >> 2, q0 = c0 & 3;
  int r1 = c1 >> 2, q1 = c1 & 3;
  int ml = lane & 15, qq = lane >> 4;

  for (int si = 0; si < segs.n; ++si) {
    const unsigned short* Aseg = segs.s[si].A;
    const unsigned short* Wseg = segs.s[si].W;
    int lda = segs.s[si].lda, ldw = segs.s[si].ldw, K = segs.s[si].K;
    for (int k0 = 0; k0 < K; k0 += 32) {
      uint4 av0 = *(const uint4*)&Aseg[(size_t)(rowBase + r0) * lda + k0 + q0 * 8];
      uint4 av1 = *(const uint4*)&Aseg[(size_t)(rowBase + r1) * lda + k0 + q1 * 8];
      uint4 wv0 = *(const uint4*)&Wseg[(size_t)(colBase + r0) * ldw + k0 + q0 * 8];
      uint4 wv1 = *(const uint4*)&Wseg[(size_t)(colBase + r1) * ldw + k0 + q1 * 8];
      __syncthreads();
      *(uint4*)&Asl[c0 * 8] = av0;
      *(uint4*)&Asl[c1 * 8] = av1;
      *(uint4*)&Wsl[c0 * 8] = wv0;
      *(uint4*)&Wsl[c1 * 8] = wv1;
      __syncthreads();
      bf16x8 af[4], bw[4];
#pragma unroll
      for (int i = 0; i < 4; ++i) {
        af[i] = *(bf16x8*)&Asl[(wm * 64 + i * 16 + ml) * 32 + qq * 8];
        bw[i] = *(bf16x8*)&Wsl[(wn * 64 + i * 16 + ml) * 32 + qq * 8];
      }
#pragma unroll
      for (int mf = 0; mf < 4; ++mf)
#pragma unroll
        for (int nf = 0; nf < 4; ++nf)
          acc[mf][nf] = __builtin_amdgcn_mfma_f32_16x16x32_bf16(af[mf], bw[nf], acc[mf][nf], 0, 0, 0);
    }
  }

  if (MODE == 0) {
    unsigned short* dst = (colBase == 0) ? Y : Z;
#pragma unroll
    for (int mf = 0; mf < 4; ++mf) {
      int row = rowBase + wm * 64 + mf * 16 + qq * 4;
#pragma unroll
      for (int nf = 0; nf < 4; ++nf) {
        int col = wn * 64 + nf * 16 + ml;
#pragma unroll
        for (int r = 0; r < 4; ++r)
          dst[(size_t)(row + r) * 128 + col] = f2h(acc[mf][nf][r]);
      }
    }
  } else {
    float bc4[4];
#pragma unroll
    for (int nf = 0; nf < 4; ++nf) bc4[nf] = bias[colBase + wn * 64 + nf * 16 + ml];
#pragma unroll
    for (int mf = 0; mf < 4; ++mf) {
      int row = rowBase + wm * 64 + mf * 16 + qq * 4;
#pragma unroll
      for (int nf = 0; nf < 4; ++nf) {
        int col = colBase + wn * 64 + nf * 16 + ml;
#pragma unroll
        for (int r = 0; r < 4; ++r) {
          float o = fmaxf(acc[mf][nf][r] + bc4[nf], 0.f);
          Ob[(size_t)(row + r) * ldc + col] = f2bf(o);
        }
      }
    }
  }
}

// ---------------- host ----------------
extern "C" void kernel_launch(void* const* d_in, const int* in_sizes, int n_in,
                              void* d_out, int out_size, void* d_ws, size_t ws_size,
                              hipStream_t stream) {
  const float* x      = (const float*)d_in[0];
  const int*   ei     = (const int*)d_in[1];
  const float* Wf_l   = (const float*)d_in[2];
  const float* bf     = (const float*)d_in[3];
  const float* Wf_r   = (const float*)d_in[4];
  const float* W0_l   = (const float*)d_in[5];
  const float* b0     = (const float*)d_in[6];
  const float* W0_r   = (const float*)d_in[7];
  const float* W1_l   = (const float*)d_in[8];
  const float* b1     = (const float*)d_in[9];
  const float* W1_r   = (const float*)d_in[10];
  const float* W_lin  = (const float*)d_in[11];
  const float* b_lin  = (const float*)d_in[12];
  const float* W_lin2 = (const float*)d_in[13];
  const float* b_lin2 = (const float*)d_in[14];
  float* out = (float*)d_out;

  const int N = in_sizes[0] / 64;           // 50000
  const int E = in_sizes[1] / 2;            // 800000
  const int Npad = ((N + 127) / 128) * 128; // 50048
  const int nblkM = Npad / 128;
  const int NB = (N + 63) / 64;             // 782 buckets
  const int G  = 64;                        // partition blocks
  const int CH = (E + G - 1) / G;           // 12500 edges/block
  const int* e_src = ei;
  const int* e_tgt = ei + E;

  size_t off = 0;
  char* base = (char*)d_ws;
  auto carve = [&](size_t bytes) -> void* {
    void* p = base + off;
    off += (bytes + 255) & ~(size_t)255;
    return p;
  };
  int*      row_ptr = (int*)carve((size_t)(N + 1) * 4);
  int*      bcnt    = (int*)carve((size_t)NB * 4);
  int*      boff    = (int*)carve((size_t)(NB + 1) * 4);
  int*      histT   = (int*)carve((size_t)NB * G * 4);
  unsigned* vals    = (unsigned*)carve((size_t)E * 4);
  int*      srcs    = (int*)carve((size_t)E * 4);
  unsigned short* xb    = (unsigned short*)carve((size_t)Npad * 64 * 2);
  unsigned short* mb    = (unsigned short*)carve((size_t)Npad * 64 * 2);
  unsigned short* h1b   = (unsigned short*)carve((size_t)Npad * 256 * 2);
  unsigned short* h2b   = (unsigned short*)carve((size_t)Npad * 128 * 2);
  unsigned short* yb    = (unsigned short*)carve((size_t)Npad * 128 * 2);
  unsigned short* zb    = (unsigned short*)carve((size_t)Npad * 128 * 2);
  unsigned short* Wt1hi = (unsigned short*)carve(256 * 128 * 2);
  unsigned short* Wt2hi = (unsigned short*)carve(256 * 256 * 2);
  unsigned short* Wt3hi = (unsigned short*)carve(256 * 128 * 2);
  float* Wcomb = (float*)carve(1024 * 4);
  float* bcomb = (float*)carve(8 * 4);
  (void)ws_size; (void)n_in; (void)out_size;

  const int nbConv = (N * 16 + 255) / 256;  // 3125
  const int nbPrep = nbConv + 128 + 256 + 128 + 4;
  const size_t ldsNB = (size_t)NB * 4;

  // CSR build: radix partition (no global atomics) + per-bucket sort (+prep merged)
  hist_k<<<G, 256, ldsNB, stream>>>(e_tgt, histT, E, NB, CH);
  scanb_k<<<(NB + 3) / 4, 256, 0, stream>>>(histT, bcnt, NB);
  bscan_k<<<1, 1024, 0, stream>>>(bcnt, boff, row_ptr, NB, E, N);
  scatter_k<<<G, 256, ldsNB, stream>>>(e_src, e_tgt, boff, histT, vals, E, NB, CH);
  bsort_prep_k<<<NB + nbPrep, 256, 0, stream>>>(
      vals, boff, row_ptr, srcs, N, NB,
      x, xb, nbConv, N * 16,
      Wf_l, Wf_r, Wt1hi,
      W0_l, W0_r, Wt2hi,
      W1_l, W1_r, Wt3hi,
      W_lin, b_lin, W_lin2, b_lin2, Wcomb, bcomb);

  const int nbAgg = (N + 3) / 4;
  const dim3 gemmGrid(nblkM, 2);

  // Layer 1: hi-only W (2 segs)
  agg_mean64_k<<<nbAgg, 256, 0, stream>>>(x, row_ptr, srcs, mb, N);
  {
    Segs s;
    s.n = 2;
    s.s[0] = {mb, Wt1hi,      64, 128, 64};
    s.s[1] = {xb, Wt1hi + 64, 64, 128, 64};
    s.s[2] = {nullptr, nullptr, 0, 0, 0};
    s.s[3] = {nullptr, nullptr, 0, 0, 0};
    gemm_mfma_k<1><<<gemmGrid, 256, 0, stream>>>(s, bf, nullptr, nullptr, h1b, 256);
  }

  // Layer 2: hi-only W
  {
    Segs s;
    s.n = 1;
    s.s[0] = {h1b, Wt2hi, 256, 256, 256};
    s.s[1] = {nullptr, nullptr, 0, 0, 0};
    s.s[2] = {nullptr, nullptr, 0, 0, 0};
    s.s[3] = {nullptr, nullptr, 0, 0, 0};
    gemm_mfma_k<0><<<gemmGrid, 256, 0, stream>>>(s, nullptr, yb, zb, nullptr, 256);
  }
  agg128_k<1><<<nbAgg, 256, 0, stream>>>(yb, zb, b0, row_ptr, srcs, h2b, nullptr, nullptr, N);

  // Layer 3 + fused head: hi-only W
  {
    Segs s;
    s.n = 1;
    s.s[0] = {h2b, Wt3hi, 128, 128, 128};
    s.s[1] = {nullptr, nullptr, 0, 0, 0};
    s.s[2] = {nullptr, nullptr, 0, 0, 0};
    s.s[3] = {nullptr, nullptr, 0, 0, 0};
    gemm_mfma_k<0><<<gemmGrid, 256, 0, stream>>>(s, nullptr, yb, zb, nullptr, 256);
  }
  agg128_k<2><<<nbAgg, 256, 0, stream>>>(yb, zb, b1, row_ptr, srcs, out, Wcomb, bcomb, N);
}